// Round 2
// 1104.300 us; speedup vs baseline: 1.1398x; 1.1398x over previous
//
#include <hip/hip_runtime.h>
#include <hip/hip_bf16.h>

typedef __hip_bfloat16 bf16;
typedef __attribute__((ext_vector_type(4))) unsigned int u32x4;
typedef __attribute__((ext_vector_type(4))) float f32x4;
typedef __attribute__((ext_vector_type(8))) short bf16x8;
#define DEV __device__ __forceinline__

// ---------------- problem constants ----------------
// N=16, C=64, H=W=160, S=25600, expanded channels 192, windows {1,3,5}
// Inputs fp32, output fp32 (confirmed rounds 3/4).

// fp32 scratch layout (offsets in floats)
constexpr int FO_Q     = 0;         // raw softmax logits, per-window concat (1239104)
constexpr int FO_SMAP  = 1239104;   // sigmoid spatial gate (1239104)
constexpr int FO_XM    = 2478208;   // per-(b,c') channel sums (560*64)
constexpr int FO_T     = 2514048;   // per-(b,c') q-weighted sums (560*64)
constexpr int FO_SIGA  = 2549888;   // per-(b,c') channel gate sigmoid(zn) (560*64)
constexpr int FO_G     = 2585728;   // per-(b,c') spatial-branch weights (560*64)
constexpr int FO_BM    = 2621568;   // per-b logit max (560)
constexpr int FO_BINV  = 2622128;   // per-b 1/sum(exp) (560)
constexpr int FO_GB    = 2622688;   // per-b spatial bias term (560)
constexpr int FO_EXPT  = 2623248;   // exp_w transposed [c*192+o] (12288)
constexpr int FO_EXPB  = 2635536;   // exp_b fp32 (192)
constexpr int FO_WBIGT = 2635728;   // combined final weight [k*64+f], k<256 (16384)
constexpr int FO_BCOMB = 2652112;   // combined final bias (64)
constexpr int FO_WFRAG = 2652176;   // bf16 A-fragment-ordered weights (16384 bf16 = 8192 f)
constexpr int FB_SIZE  = 2660368;

__device__ unsigned short g_ex_u[78643200]; // 16*192*25600 bf16
__device__ float          g_fb[FB_SIZE];

template<int WIN> struct WP;
template<> struct WP<1> { static constexpr int WI=0, SH=160, KH=160, K=25600, P=1,  B=16,  QOFF=0,      BOFF=0,   CHUNKS=13; };
template<> struct WP<3> { static constexpr int WI=1, SH=53,  KH=54,  K=2916,  P=9,  B=144, QOFF=409600, BOFF=16,  CHUNKS=2;  };
template<> struct WP<5> { static constexpr int WI=2, SH=32,  KH=32,  K=1024,  P=25, B=400, QOFF=829504, BOFF=160, CHUNKS=1;  };

// psa-space walk helpers (used by pass kernels)
template<int WIN> DEV void decomp(int f, int& c, int& kidx, int& p) {
  constexpr int P = WP<WIN>::P, K = WP<WIN>::K;
  int m;
  if constexpr (P == 1) { p = 0; m = f; }
  else { m = f / P; p = f - m * P; }
  c = m / K; kidx = m - c * K;
}

template<int WIN> DEV void stepK(int& c, int& kidx, int& p) {  // f += K
  constexpr int K = WP<WIN>::K, P = WP<WIN>::P;
  if constexpr (P == 1) { kidx += K; }
  else {
    constexpr int KMP = K % P, KDP = K / P;
    if constexpr (KMP == 0) { kidx += KDP; }
    else { p += KMP; if (p >= P) { p -= P; kidx += KDP + 1; } else kidx += KDP; }
  }
  if (kidx >= K) { kidx -= K; ++c; }
}

template<int WIN> DEV int pix(int kidx, int p) {
  constexpr int KH = WP<WIN>::KH, SH = WP<WIN>::SH;
  if constexpr (WIN == 1) return kidx;
  int ki = kidx / KH, kj = kidx - ki * KH;
  int ph = p / WIN,  pw = p - ph * WIN;
  return (ph * SH + ki) * 160 + pw * SH + kj;
}

DEV unsigned short bfbits(float f) {
  bf16 b = __float2bfloat16(f);
  unsigned short u;
  __builtin_memcpy(&u, &b, 2);
  return u;
}

DEV void store8bf(bf16* p, const unsigned short* ob) {
  u32x4 v = { (unsigned)ob[0] | ((unsigned)ob[1] << 16),
              (unsigned)ob[2] | ((unsigned)ob[3] << 16),
              (unsigned)ob[4] | ((unsigned)ob[5] << 16),
              (unsigned)ob[6] | ((unsigned)ob[7] << 16) };
  *(u32x4*)p = v;
}

DEV bf16x8 as_bf16x8(u32x4 v) {
  union { u32x4 u; bf16x8 b; } x; x.u = v; return x.b;
}

// ---------------- k_prep ----------------
__global__ __launch_bounds__(256)
void k_prep(const float* __restrict__ exp_w, const float* __restrict__ exp_b,
            const float* __restrict__ res_w, const float* __restrict__ res_b,
            const float* __restrict__ fus_w, const float* __restrict__ fus_b) {
  float* fb = g_fb;
  int gt = blockIdx.x * 256 + threadIdx.x;
  if (gt < 12288) {                       // Wcomb[f][oc] = sum_o fus[f][o]*res[o][oc]
    int oc = gt % 192, f = gt / 192;
    float a = 0.f;
    for (int o = 0; o < 64; ++o)
      a += fus_w[f*64+o] * res_w[o*192+oc];
    fb[FO_WBIGT + oc*64 + f] = a;
  } else if (gt < 16384) {                // rows 192..255: fus_w
    int t2 = gt - 12288; int o = t2 % 64, f = t2 / 64;
    fb[FO_WBIGT + (192+o)*64 + f] = fus_w[f*64+o];
  } else if (gt < 16448) {                // bcomb
    int f = gt - 16384;
    float a = fus_b[f];
    for (int o = 0; o < 64; ++o)
      a += fus_w[f*64+o] * res_b[o];
    fb[FO_BCOMB + f] = a;
  } else if (gt < 28736) {                // expT[c*192+o] = exp_w[o][c]
    int t3 = gt - 16448; int o = t3 % 192, c = t3 / 192;
    fb[FO_EXPT + c*192 + o] = exp_w[o*64+c];
  } else if (gt < 28928) {
    int o = gt - 28736;
    fb[FO_EXPB + o] = exp_b[o];
  } else if (gt < 28928 + 71680) {        // zero xm and t (contiguous)
    fb[FO_XM + gt - 28928] = 0.f;
  }
}

// ---------------- k_prep2: bake bf16 A-fragments for the final MFMA ----------
// layout: element index ((wv*8 + ks)*64 + lane)*8 + j
//   holds Wcomb_bf16[k = ks*32 + (lane>>4)*8 + j][o = wv*16 + (lane&15)]
// (same k-slot bijection as the B-side ds_read_b128 path, so only the
//  lane->row/col and C/D mappings are load-bearing)
__global__ __launch_bounds__(256)
void k_prep2() {
  float* fb = g_fb;
  bf16* wf = (bf16*)(fb + FO_WFRAG);
  int t = blockIdx.x * 256 + threadIdx.x;     // 0..16383
  int j  = t & 7;
  int l  = (t >> 3) & 63;
  int ks = (t >> 9) & 7;
  int wv = t >> 12;
  int k = ks*32 + (l >> 4)*8 + j;
  int o = wv*16 + (l & 15);
  wf[t] = __float2bfloat16(fb[FO_WBIGT + k*64 + o]);
}

// ---------------- k_ex: ex = conv1x1(x, exp_w, exp_b), bf16 out ----------------
__global__ __launch_bounds__(256)
void k_ex(const float* __restrict__ x) {
  const float* fb = g_fb;
  bf16* ex = (bf16*)g_ex_u;
  __shared__ float xs[64*64];
  int blk = blockIdx.x; int n = blk / 400; int s0 = (blk % 400) * 64;
  int tid = threadIdx.x;
  for (int e = tid; e < 4096; e += 256) {
    int c = e >> 6, px = e & 63;
    xs[e] = x[(n*64 + c)*25600 + s0 + px];
  }
  __syncthreads();
  int px = tid & 63;
  int o0 = __builtin_amdgcn_readfirstlane((tid >> 6) * 48);
  float acc[48];
#pragma unroll
  for (int j = 0; j < 48; ++j) acc[j] = fb[FO_EXPB + o0 + j];
  const float* wT = fb + FO_EXPT;
  for (int c = 0; c < 64; ++c) {
    float xv = xs[(c << 6) + px];
    const float* wr = wT + c*192 + o0;
#pragma unroll
    for (int j = 0; j < 48; ++j) acc[j] += wr[j] * xv;
  }
  bf16* eo = ex + (size_t)(n*192 + o0)*25600 + s0 + px;
#pragma unroll
  for (int j = 0; j < 48; ++j) eo[(size_t)j*25600] = __float2bfloat16(acc[j]);
}

// ---------------- k_pass1: fused logit + xm (one ex read) ----------------
// 4 waves; wave w owns channels [16w,16w+16); all waves share the same sp.
template<int WIN> __global__ __launch_bounds__(256)
void k_pass1(const float* __restrict__ chq_w, const float* __restrict__ chq_b) {
  using W = WP<WIN>;
  constexpr int K = W::K, P = W::P, CK = 64*K, WI = W::WI, QOFF = W::QOFF,
                BOFF = W::BOFF, CH = W::CHUNKS;
  float* fb = g_fb;
  const bf16* ex = (const bf16*)g_ex_u;
  __shared__ float dots[256];
  int tid = threadIdx.x, lane = tid & 63; int c0 = (tid >> 6) * 16;
  int blk = blockIdx.x; int bi = blk / CH; int ch = blk - bi*CH;
  int n = bi / P, bl = bi - n*P; int bg = BOFF + bi;
  int send = ((ch+1)*2048 < K) ? (ch+1)*2048 : K;
  const bf16* exn = ex + (size_t)(n*192 + WI*64)*25600;
  float* qout = fb + FO_Q + QOFF + (size_t)bi*K;
  float wqr[16];
#pragma unroll
  for (int j = 0; j < 16; ++j) wqr[j] = chq_w[c0 + j];
  float wqb = chq_b[0];
  float part[16];
#pragma unroll
  for (int j = 0; j < 16; ++j) part[j] = 0.f;
  for (int spb = ch*2048; spb < send; spb += 64) {
    int sp = spb + lane;
    float dot = 0.f;
    if (sp < send) {
      int f = bl*CK + c0*K + sp;
      int c, kidx, p; decomp<WIN>(f, c, kidx, p);
#pragma unroll
      for (int j = 0; j < 16; ++j) {
        float v = __bfloat162float(exn[c*25600 + pix<WIN>(kidx, p)]);
        part[j] += v;
        dot += wqr[j] * v;
        stepK<WIN>(c, kidx, p);
      }
    }
    dots[tid] = dot;
    __syncthreads();
    if (tid < 64 && spb + tid < send)
      qout[spb + tid] = dots[tid] + dots[64+tid] + dots[128+tid] + dots[192+tid] + wqb;
    __syncthreads();
  }
#pragma unroll
  for (int j = 0; j < 16; ++j) {
    float v = part[j];
    for (int off = 32; off; off >>= 1) v += __shfl_xor(v, off, 64);
    if (lane == 0) atomicAdd(&fb[FO_XM + bg*64 + c0 + j], v);
  }
}

// ---------------- k_bstats: per-b softmax stats + spatial branch ----------------
__global__ __launch_bounds__(256)
void k_bstats(const float* __restrict__ spq_w, const float* __restrict__ spq_b,
              const float* __restrict__ spv_w, const float* __restrict__ spv_b) {
  float* fb = g_fb;
  __shared__ float red[256]; __shared__ float sqs[32]; __shared__ float swq[32];
  int bg = blockIdx.x, tid = threadIdx.x;
  int Kk, qo, bi;
  if (bg < 16)       { Kk = 25600; qo = 0;      bi = bg;       }
  else if (bg < 160) { Kk = 2916;  qo = 409600; bi = bg - 16;  }
  else               { Kk = 1024;  qo = 829504; bi = bg - 160; }
  const float* lg = fb + FO_Q + qo + (size_t)bi*Kk;
  float m = -1e30f;
  for (int s = tid; s < Kk; s += 256) m = fmaxf(m, lg[s]);
  red[tid] = m; __syncthreads();
  for (int st = 128; st; st >>= 1) { if (tid < st) red[tid] = fmaxf(red[tid], red[tid+st]); __syncthreads(); }
  float M = red[0]; __syncthreads();
  float ss = 0.f;
  for (int s = tid; s < Kk; s += 256) ss += __expf(lg[s] - M);
  red[tid] = ss; __syncthreads();
  for (int st = 128; st; st >>= 1) { if (tid < st) red[tid] += red[tid+st]; __syncthreads(); }
  if (tid == 0) { fb[FO_BM + bg] = M; fb[FO_BINV + bg] = 1.f / red[0]; }
  const float* xm_b = fb + FO_XM + bg*64;
  float rK = 1.f / (float)Kk;
  if (tid < 32) {
    float a = spq_b[tid];
    for (int c = 0; c < 64; ++c)
      a += spq_w[tid*64 + c] * (xm_b[c] * rK);
    sqs[tid] = a;
  }
  __syncthreads();
  if (tid == 0) {
    float mx = -1e30f;
    for (int o = 0; o < 32; ++o) mx = fmaxf(mx, sqs[o]);
    float z = 0.f;
    for (int o = 0; o < 32; ++o) { float e = __expf(sqs[o] - mx); swq[o] = e; z += e; }
    float rz = 1.f / z;
    for (int o = 0; o < 32; ++o) swq[o] *= rz;
  }
  __syncthreads();
  if (tid < 64) {
    float a = 0.f;
    for (int o = 0; o < 32; ++o) a += swq[o] * spv_w[o*64 + tid];
    fb[FO_G + bg*64 + tid] = a;
  }
  if (tid == 64) {
    float gb = 0.f;
    for (int o = 0; o < 32; ++o) gb += swq[o] * spv_b[o];
    fb[FO_GB + bg] = gb;
  }
}

// ---------------- k_pass2: fused t + smap (one ex read) ----------------
template<int WIN> __global__ __launch_bounds__(256)
void k_pass2() {
  using W = WP<WIN>;
  constexpr int K = W::K, P = W::P, CK = 64*K, WI = W::WI, QOFF = W::QOFF,
                BOFF = W::BOFF, CH = W::CHUNKS;
  float* fb = g_fb;
  const bf16* ex = (const bf16*)g_ex_u;
  __shared__ float dots[256];
  int tid = threadIdx.x, lane = tid & 63; int c0 = (tid >> 6) * 16;
  int blk = blockIdx.x; int bi = blk / CH; int ch = blk - bi*CH;
  int n = bi / P, bl = bi - n*P; int bg = BOFF + bi;
  int send = ((ch+1)*2048 < K) ? (ch+1)*2048 : K;
  const bf16* exn = ex + (size_t)(n*192 + WI*64)*25600;
  const float* qin = fb + FO_Q + QOFF + (size_t)bi*K;
  float* so = fb + FO_SMAP + QOFF + (size_t)bi*K;
  float M = fb[FO_BM + bg], inv = fb[FO_BINV + bg];
  float gsr[16];
#pragma unroll
  for (int j = 0; j < 16; ++j) gsr[j] = fb[FO_G + bg*64 + c0 + j];
  float gbs = fb[FO_GB + bg];
  float part[16];
#pragma unroll
  for (int j = 0; j < 16; ++j) part[j] = 0.f;
  for (int spb = ch*2048; spb < send; spb += 64) {
    int sp = spb + lane;
    float dot = 0.f;
    if (sp < send) {
      float qv = __expf(qin[sp] - M) * inv;
      int f = bl*CK + c0*K + sp;
      int c, kidx, p; decomp<WIN>(f, c, kidx, p);
#pragma unroll
      for (int j = 0; j < 16; ++j) {
        float v = __bfloat162float(exn[c*25600 + pix<WIN>(kidx, p)]);
        part[j] += qv * v;
        dot += gsr[j] * v;
        stepK<WIN>(c, kidx, p);
      }
    }
    dots[tid] = dot;
    __syncthreads();
    if (tid < 64 && spb + tid < send) {
      float d = dots[tid] + dots[64+tid] + dots[128+tid] + dots[192+tid] + gbs;
      so[spb + tid] = 1.f / (1.f + __expf(-d));
    }
    __syncthreads();
  }
#pragma unroll
  for (int j = 0; j < 16; ++j) {
    float v = part[j];
    for (int off = 32; off; off >>= 1) v += __shfl_xor(v, off, 64);
    if (lane == 0) atomicAdd(&fb[FO_T + bg*64 + c0 + j], v);
  }
}

// ---------------- k_zln: wz -> z -> LayerNorm -> sigA ----------------
__global__ __launch_bounds__(64)
void k_zln(const float* __restrict__ chv_w, const float* __restrict__ chv_b,
           const float* __restrict__ chz_w, const float* __restrict__ chz_b,
           const float* __restrict__ ln_g,  const float* __restrict__ ln_b) {
  float* fb = g_fb;
  __shared__ float wzs[32]; __shared__ float zsh[64]; __shared__ float mom[2];
  int bg = blockIdx.x, tid = threadIdx.x;
  const float* t_b = fb + FO_T + bg*64;
  if (tid < 32) {
    float a = chv_b[tid];
    for (int c = 0; c < 64; ++c)
      a += chv_w[tid*64 + c] * t_b[c];
    wzs[tid] = a;
  }
  __syncthreads();
  float zv = chz_b[tid];
  for (int o = 0; o < 32; ++o)
    zv += chz_w[tid*32 + o] * wzs[o];
  zsh[tid] = zv;
  __syncthreads();
  if (tid == 0) {
    float mu = 0.f;
    for (int j = 0; j < 64; ++j) mu += zsh[j];
    mu *= (1.f/64.f);
    float m2 = 0.f;
    for (int j = 0; j < 64; ++j) { float d = zsh[j] - mu; m2 += d*d; }
    m2 *= (1.f/64.f);
    mom[0] = mu; mom[1] = rsqrtf(m2 + 1e-5f);
  }
  __syncthreads();
  float zn = (zv - mom[0]) * mom[1] * ln_g[tid] + ln_b[tid];
  fb[FO_SIGA + bg*64 + tid] = 1.f / (1.f + __expf(-zn));
}

// ---------------- k_final: gates -> extT (bf16, swizzled LDS) -> MFMA conv ----
// Gate algebra (per window): f = c*K*P + base0, base0 = q*K + s0 =>
//   sp = s0 (const in c), cf = c*P + q, siga idx = cf (LDS-staged),
//   smap idx = (cf>>6)*K + s0 (changes only when cf>>6 steps -> hoisted).
// LDS tile layout: extT[px][k] bf16, element index px*256 + (k ^ ((px&7)<<3))
// (XOR swizzle, 8-element granular -> ds_read_b128/ds_write_b128 both minimal).
template<int WIN> DEV void gate_rows2(int n, int h, int w, int px,
                                      const bf16* __restrict__ ex,
                                      const float* __restrict__ fb,
                                      bf16* extT, const float* sg) {
  using W = WP<WIN>;
  constexpr int SH = W::SH, KH = W::KH, K = W::K, P = W::P, WI = W::WI,
                QOFF = W::QOFF;
  int s = h*160 + w;
  const bf16* exr = ex + (size_t)(n*192 + WI*64)*25600 + s;
  const float* smap = fb + FO_SMAP + QOFF + (size_t)(n*P)*K;
  int swz = (px & 7) << 3;
  unsigned short ob[8];
  if constexpr (WIN == 1) {
    float sm = smap[s];
    for (int c0 = 0; c0 < 64; c0 += 8) {
#pragma unroll
      for (int cc = 0; cc < 8; ++cc) {
        int c = c0 + cc;
        float exv = __bfloat162float(exr[(size_t)c*25600]);
        ob[cc] = bfbits(exv * (1.f + sg[c] + sm));
      }
      store8bf(&extT[px*256 + ((WI*64 + c0) ^ swz)], ob);
    }
  } else {
    int phmin = (h >= KH) ? (h - KH)/SH + 1 : 0;
    int phmax = (WIN-1 < h/SH) ? WIN-1 : h/SH;
    int pwmin = (w >= KH) ? (w - KH)/SH + 1 : 0;
    int pwmax = (WIN-1 < w/SH) ? WIN-1 : w/SH;
    int cf[4]; int s0s[4]; int np = 0;
    for (int ph = phmin; ph <= phmax; ++ph)
      for (int pw = pwmin; pw <= pwmax; ++pw) {
        int ki = h - ph*SH, kj = w - pw*SH;
        unsigned base0 = (unsigned)((ki*KH + kj)*P + ph*WIN + pw);
        unsigned q = base0 / (unsigned)K;
        cf[np] = (int)q; s0s[np] = (int)(base0 - q*(unsigned)K); ++np;
      }
    float rc = 1.f / (float)np;
    int hi[4]; float smv[4];
#pragma unroll
    for (int t = 0; t < 4; ++t)
      if (t < np) { hi[t] = cf[t] >> 6; smv[t] = smap[hi[t]*K + s0s[t]]; }
    for (int c0 = 0; c0 < 64; c0 += 8) {
#pragma unroll
      for (int cc = 0; cc < 8; ++cc) {
        float gsum = 0.f;
#pragma unroll
        for (int t = 0; t < 4; ++t) {
          if (t < np) {
            int v = cf[t];
            int h2 = v >> 6;
            if (h2 != hi[t]) { hi[t] = h2; smv[t] = smap[h2*K + s0s[t]]; }
            gsum += sg[v] + smv[t];
            cf[t] = v + P;
          }
        }
        int c = c0 + cc;
        float exv = __bfloat162float(exr[(size_t)c*25600]);
        ob[cc] = bfbits(exv * (1.f + gsum * rc));
      }
      store8bf(&extT[px*256 + ((WI*64 + c0) ^ swz)], ob);
    }
  }
}

__global__ __launch_bounds__(256)
void k_final(const float* __restrict__ x, float* __restrict__ out) {
  const float* fb = g_fb;
  const bf16* ex = (const bf16*)g_ex_u;
  __shared__ __align__(16) bf16 extT[64*256];   // [px][k] swizzled, 32 KB
  __shared__ float sigaS[2240];     // win1: 0..63, win3: 64..639, win5: 640..2239
  int blk = blockIdx.x; int n = blk / 400; int s0 = (blk % 400) * 64;
  int tid = threadIdx.x;
  {
    const float* s1 = fb + FO_SIGA + n*64;
    const float* s3 = fb + FO_SIGA + (16 + n*9)*64;
    const float* s5 = fb + FO_SIGA + (160 + n*25)*64;
    if (tid < 64) sigaS[tid] = s1[tid];
    for (int i = tid; i < 576; i += 256) sigaS[64 + i] = s3[i];
    for (int i = tid; i < 1600; i += 256) sigaS[640 + i] = s5[i];
  }
  __syncthreads();
  int rg = tid >> 6; int px = tid & 63;
  int s = s0 + px; int h = s / 160; int w = s - h*160;
  if (rg == 3) {
    int swz = (px & 7) << 3;
    unsigned short ob[8];
    for (int c0 = 0; c0 < 64; c0 += 8) {
#pragma unroll
      for (int cc = 0; cc < 8; ++cc)
        ob[cc] = bfbits(x[(size_t)(n*64 + c0 + cc)*25600 + s]);
      store8bf(&extT[px*256 + ((192 + c0) ^ swz)], ob);
    }
  } else if (rg == 0) gate_rows2<1>(n, h, w, px, ex, fb, extT, sigaS);
  else if (rg == 1)   gate_rows2<3>(n, h, w, px, ex, fb, extT, sigaS + 64);
  else                gate_rows2<5>(n, h, w, px, ex, fb, extT, sigaS + 640);
  __syncthreads();

  // ---- MFMA: out[o][px] = sum_k W[k][o] * extT[px][k], K=256 ----
  // A = W fragment (o rows), B = extT (px cols); both sides use the same
  // k-slot bijection so only lane->row/col + C/D layouts are assumed.
  int wv = tid >> 6; int l = tid & 63;
  int lx = l & 15, g = l >> 4;
  const u32x4* wfA = (const u32x4*)(fb + FO_WFRAG);
  u32x4 af[8];
#pragma unroll
  for (int ks = 0; ks < 8; ++ks) af[ks] = wfA[(wv*8 + ks)*64 + l];
  f32x4 acc[4];
#pragma unroll
  for (int pt = 0; pt < 4; ++pt) acc[pt] = f32x4{0.f, 0.f, 0.f, 0.f};
#pragma unroll
  for (int ks = 0; ks < 8; ++ks) {
#pragma unroll
    for (int pt = 0; pt < 4; ++pt) {
      int pxx = pt*16 + lx;
      const u32x4* bp = (const u32x4*)&extT[pxx*256 + ((ks*32 + g*8) ^ ((pxx & 7) << 3))];
      acc[pt] = __builtin_amdgcn_mfma_f32_16x16x32_bf16(
                  as_bf16x8(af[ks]), as_bf16x8(*bp), acc[pt], 0, 0, 0);
    }
  }
  float bia[4];
#pragma unroll
  for (int r = 0; r < 4; ++r) bia[r] = fb[FO_BCOMB + wv*16 + g*4 + r];
#pragma unroll
  for (int pt = 0; pt < 4; ++pt) {
#pragma unroll
    for (int r = 0; r < 4; ++r)
      out[(size_t)(n*64 + wv*16 + g*4 + r)*25600 + s0 + pt*16 + lx] = acc[pt][r] + bia[r];
  }
}

// ---------------- launch ----------------
extern "C" void kernel_launch(void* const* d_in, const int* in_sizes, int n_in,
                              void* d_out, int out_size, void* d_ws, size_t ws_size,
                              hipStream_t stream) {
  const float* x     = (const float*)d_in[0];
  const float* exp_w = (const float*)d_in[1];
  const float* exp_b = (const float*)d_in[2];
  const float* res_w = (const float*)d_in[3];
  const float* res_b = (const float*)d_in[4];
  const float* fus_w = (const float*)d_in[5];
  const float* fus_b = (const float*)d_in[6];
  const float* chv_w = (const float*)d_in[7];
  const float* chv_b = (const float*)d_in[8];
  const float* chq_w = (const float*)d_in[9];
  const float* chq_b = (const float*)d_in[10];
  const float* chz_w = (const float*)d_in[11];
  const float* chz_b = (const float*)d_in[12];
  const float* ln_g  = (const float*)d_in[13];
  const float* ln_b  = (const float*)d_in[14];
  const float* spv_w = (const float*)d_in[15];
  const float* spv_b = (const float*)d_in[16];
  const float* spq_w = (const float*)d_in[17];
  const float* spq_b = (const float*)d_in[18];
  float* out = (float*)d_out;

  k_prep<<<393, 256, 0, stream>>>(exp_w, exp_b, res_w, res_b, fus_w, fus_b);
  k_prep2<<<64, 256, 0, stream>>>();
  k_ex<<<6400, 256, 0, stream>>>(x);

  k_pass1<1><<<208, 256, 0, stream>>>(chq_w, chq_b);
  k_pass1<3><<<288, 256, 0, stream>>>(chq_w, chq_b);
  k_pass1<5><<<400, 256, 0, stream>>>(chq_w, chq_b);

  k_bstats<<<560, 256, 0, stream>>>(spq_w, spq_b, spv_w, spv_b);

  k_pass2<1><<<208, 256, 0, stream>>>();
  k_pass2<3><<<288, 256, 0, stream>>>();
  k_pass2<5><<<400, 256, 0, stream>>>();

  k_zln<<<560, 64, 0, stream>>>(chv_w, chv_b, chz_w, chz_b, ln_g, ln_b);

  k_final<<<6400, 256, 0, stream>>>(x, out);
}

// Round 3
// 838.446 us; speedup vs baseline: 1.5012x; 1.3171x over previous
//
#include <hip/hip_runtime.h>
#include <hip/hip_bf16.h>

typedef __hip_bfloat16 bf16;
typedef __attribute__((ext_vector_type(4))) unsigned int u32x4;
typedef __attribute__((ext_vector_type(4))) float f32x4;
typedef __attribute__((ext_vector_type(8))) short bf16x8;
#define DEV __device__ __forceinline__

// ---------------- problem constants ----------------
// N=16, C=64, H=W=160, S=25600, expanded channels 192, windows {1,3,5}

// fp32 scratch layout (offsets in floats)
constexpr int FO_Q     = 0;         // raw softmax logits, per-window concat (1239104)
constexpr int FO_SMAP  = 1239104;   // sigmoid spatial gate (1239104)
constexpr int FO_XM    = 2478208;   // per-(b,c') channel sums (560*64)
constexpr int FO_T     = 2514048;   // per-(b,c') q-weighted sums (560*64)
constexpr int FO_SIGA  = 2549888;   // per-(b,c') channel gate sigmoid(zn) (560*64)
constexpr int FO_G     = 2585728;   // per-(b,c') spatial-branch weights (560*64)
constexpr int FO_BM    = 2621568;   // per-b logit max (560)
constexpr int FO_BINV  = 2622128;   // per-b 1/sum(exp) (560)
constexpr int FO_GB    = 2622688;   // per-b spatial bias term (560)
constexpr int FO_EXPT  = 2623248;   // exp_w transposed [c*192+o] (12288)
constexpr int FO_EXPB  = 2635536;   // exp_b fp32 (192)
constexpr int FO_WBIGT = 2635728;   // combined final weight [k*64+f], k<256 (16384)
constexpr int FO_BCOMB = 2652112;   // combined final bias (64)
constexpr int FO_WFRAG = 2652176;   // bf16 A-fragment-ordered weights (16384 bf16 = 8192 f)
constexpr int FB_SIZE  = 2660368;

__device__ unsigned short g_ex_u[78643200]; // 16*192*25600 bf16
__device__ float          g_fb[FB_SIZE];

template<int WIN> struct WP;
template<> struct WP<1> { static constexpr int WI=0, SH=160, KH=160, K=25600, P=1,  B=16,  QOFF=0,      BOFF=0;   };
template<> struct WP<3> { static constexpr int WI=1, SH=53,  KH=54,  K=2916,  P=9,  B=144, QOFF=409600, BOFF=16;  };
template<> struct WP<5> { static constexpr int WI=2, SH=32,  KH=32,  K=1024,  P=25, B=400, QOFF=829504, BOFF=160; };

// psa-space walk helpers (used by pass kernels)
template<int WIN> DEV void decomp(int f, int& c, int& kidx, int& p) {
  constexpr int P = WP<WIN>::P, K = WP<WIN>::K;
  int m;
  if constexpr (P == 1) { p = 0; m = f; }
  else { m = f / P; p = f - m * P; }
  c = m / K; kidx = m - c * K;
}

template<int WIN> DEV void stepK(int& c, int& kidx, int& p) {  // f += K
  constexpr int K = WP<WIN>::K, P = WP<WIN>::P;
  if constexpr (P == 1) { kidx += K; }
  else {
    constexpr int KMP = K % P, KDP = K / P;
    if constexpr (KMP == 0) { kidx += KDP; }
    else { p += KMP; if (p >= P) { p -= P; kidx += KDP + 1; } else kidx += KDP; }
  }
  if (kidx >= K) { kidx -= K; ++c; }
}

template<int WIN> DEV int pix(int kidx, int p) {
  constexpr int KH = WP<WIN>::KH, SH = WP<WIN>::SH;
  if constexpr (WIN == 1) return kidx;
  int ki = kidx / KH, kj = kidx - ki * KH;
  int ph = p / WIN,  pw = p - ph * WIN;
  return (ph * SH + ki) * 160 + pw * SH + kj;
}

DEV unsigned short bfbits(float f) {
  bf16 b = __float2bfloat16(f);
  unsigned short u;
  __builtin_memcpy(&u, &b, 2);
  return u;
}

DEV void store8bf(bf16* p, const unsigned short* ob) {
  u32x4 v = { (unsigned)ob[0] | ((unsigned)ob[1] << 16),
              (unsigned)ob[2] | ((unsigned)ob[3] << 16),
              (unsigned)ob[4] | ((unsigned)ob[5] << 16),
              (unsigned)ob[6] | ((unsigned)ob[7] << 16) };
  *(u32x4*)p = v;
}

DEV bf16x8 as_bf16x8(u32x4 v) {
  union { u32x4 u; bf16x8 b; } x; x.u = v; return x.b;
}

// Butterfly reduce: part[c] summed across the 64 lanes of a wave; ends with
// lane l holding the total for channel bitrev6(l); one coalesced atomic.
DEV void wave_reduce64_atomic(float* dst, float (&part)[64], int lane) {
#pragma unroll
  for (int s = 0; s < 6; ++s) {
    const int m = 1 << s, half = 32 >> s;
#pragma unroll
    for (int i = 0; i < half; ++i) {
      float lo = part[i], hi = part[i + half];
      float keep = (lane & m) ? hi : lo;
      float sv   = (lane & m) ? lo : hi;
      float recv = __shfl_xor(sv, m, 64);
      part[i] = keep + recv;
    }
  }
  int chn = (int)(__brev((unsigned)lane) >> 26);
  atomicAdd(dst + chn, part[0]);
}

// ---------------- k_prep ----------------
__global__ __launch_bounds__(256)
void k_prep(const float* __restrict__ exp_w, const float* __restrict__ exp_b,
            const float* __restrict__ res_w, const float* __restrict__ res_b,
            const float* __restrict__ fus_w, const float* __restrict__ fus_b) {
  float* fb = g_fb;
  int gt = blockIdx.x * 256 + threadIdx.x;
  if (gt < 12288) {                       // Wcomb[f][oc] = sum_o fus[f][o]*res[o][oc]
    int oc = gt % 192, f = gt / 192;
    float a = 0.f;
    for (int o = 0; o < 64; ++o)
      a += fus_w[f*64+o] * res_w[o*192+oc];
    fb[FO_WBIGT + oc*64 + f] = a;
  } else if (gt < 16384) {                // rows 192..255: fus_w
    int t2 = gt - 12288; int o = t2 % 64, f = t2 / 64;
    fb[FO_WBIGT + (192+o)*64 + f] = fus_w[f*64+o];
  } else if (gt < 16448) {                // bcomb
    int f = gt - 16384;
    float a = fus_b[f];
    for (int o = 0; o < 64; ++o)
      a += fus_w[f*64+o] * res_b[o];
    fb[FO_BCOMB + f] = a;
  } else if (gt < 28736) {                // expT[c*192+o] = exp_w[o][c]
    int t3 = gt - 16448; int o = t3 % 192, c = t3 / 192;
    fb[FO_EXPT + c*192 + o] = exp_w[o*64+c];
  } else if (gt < 28928) {
    int o = gt - 28736;
    fb[FO_EXPB + o] = exp_b[o];
  } else if (gt < 28928 + 71680) {        // zero xm and t (contiguous)
    fb[FO_XM + gt - 28928] = 0.f;
  }
}

// ---------------- k_prep2: bake bf16 A-fragments for the final MFMA ----------
__global__ __launch_bounds__(256)
void k_prep2() {
  float* fb = g_fb;
  bf16* wf = (bf16*)(fb + FO_WFRAG);
  int t = blockIdx.x * 256 + threadIdx.x;     // 0..16383
  int j  = t & 7;
  int l  = (t >> 3) & 63;
  int ks = (t >> 9) & 7;
  int wv = t >> 12;
  int k = ks*32 + (l >> 4)*8 + j;
  int o = wv*16 + (l & 15);
  wf[t] = __float2bfloat16(fb[FO_WBIGT + k*64 + o]);
}

// ---------------- k_ex: ex = conv1x1(x, exp_w, exp_b), bf16 out ----------------
__global__ __launch_bounds__(256)
void k_ex(const float* __restrict__ x) {
  const float* fb = g_fb;
  bf16* ex = (bf16*)g_ex_u;
  __shared__ float xs[64*64];
  int blk = blockIdx.x; int n = blk / 400; int s0 = (blk % 400) * 64;
  int tid = threadIdx.x;
  for (int e = tid; e < 4096; e += 256) {
    int c = e >> 6, px = e & 63;
    xs[e] = x[(n*64 + c)*25600 + s0 + px];
  }
  __syncthreads();
  int px = tid & 63;
  int o0 = __builtin_amdgcn_readfirstlane((tid >> 6) * 48);
  float acc[48];
#pragma unroll
  for (int j = 0; j < 48; ++j) acc[j] = fb[FO_EXPB + o0 + j];
  const float* wT = fb + FO_EXPT;
  for (int c = 0; c < 64; ++c) {
    float xv = xs[(c << 6) + px];
    const float* wr = wT + c*192 + o0;
#pragma unroll
    for (int j = 0; j < 48; ++j) acc[j] += wr[j] * xv;
  }
  bf16* eo = ex + (size_t)(n*192 + o0)*25600 + s0 + px;
#pragma unroll
  for (int j = 0; j < 48; ++j) eo[(size_t)j*25600] = __float2bfloat16(acc[j]);
}

// ---------------- k_p1all: fused logit + xm, barrier-free, all windows ------
// Each lane owns one sp and walks all 64 psa-channels.
template<int WIN, int CH, int CHUNK, int ITERS>
DEV void p1_body(int idx, const float* __restrict__ chq_w, float wqb) {
  using W = WP<WIN>;
  constexpr int K = W::K, P = W::P, CK = 64*K, WI = W::WI, QOFF = W::QOFF,
                BOFF = W::BOFF;
  float* fb = g_fb;
  const bf16* ex = (const bf16*)g_ex_u;
  int bi = idx / CH, ch = idx - bi*CH;
  int n = bi / P, bl = bi - n*P; int bg = BOFF + bi;
  int base = ch*CHUNK;
  int send = (base + CHUNK < K) ? base + CHUNK : K;
  const bf16* exn = ex + (size_t)(n*192 + WI*64)*25600;
  float* qout = fb + FO_Q + QOFF + (size_t)bi*K;
  int tid = threadIdx.x, lane = tid & 63;
  float wq[64];
#pragma unroll
  for (int j = 0; j < 64; ++j) wq[j] = chq_w[j];
  float part[64];
#pragma unroll
  for (int j = 0; j < 64; ++j) part[j] = 0.f;
  for (int it = 0; it < ITERS; ++it) {
    int sp = base + it*256 + tid;
    if (sp < send) {
      int f = bl*CK + sp;
      int c, kidx, p; decomp<WIN>(f, c, kidx, p);
      float dot = 0.f;
#pragma unroll
      for (int j = 0; j < 64; ++j) {
        float v = __bfloat162float(exn[c*25600 + pix<WIN>(kidx, p)]);
        part[j] += v;
        dot += wq[j] * v;
        stepK<WIN>(c, kidx, p);
      }
      qout[sp] = dot + wqb;
    }
  }
  wave_reduce64_atomic(fb + FO_XM + bg*64, part, lane);
}

__global__ __launch_bounds__(256, 2)
void k_p1all(const float* __restrict__ chq_w, const float* __restrict__ chq_b) {
  float wqb = chq_b[0];
  int blk = blockIdx.x;
  if (blk < 400)      p1_body<1,25,1024,4>(blk,       chq_w, wqb);
  else if (blk < 832) p1_body<3, 3, 972,4>(blk - 400, chq_w, wqb);
  else                p1_body<5, 2, 512,2>(blk - 832, chq_w, wqb);
}

// ---------------- k_bstats: per-b softmax stats + spatial branch ----------------
__global__ __launch_bounds__(256)
void k_bstats(const float* __restrict__ spq_w, const float* __restrict__ spq_b,
              const float* __restrict__ spv_w, const float* __restrict__ spv_b) {
  float* fb = g_fb;
  __shared__ float red[256]; __shared__ float sqs[32]; __shared__ float swq[32];
  int bg = blockIdx.x, tid = threadIdx.x;
  int Kk, qo, bi;
  if (bg < 16)       { Kk = 25600; qo = 0;      bi = bg;       }
  else if (bg < 160) { Kk = 2916;  qo = 409600; bi = bg - 16;  }
  else               { Kk = 1024;  qo = 829504; bi = bg - 160; }
  const float* lg = fb + FO_Q + qo + (size_t)bi*Kk;
  float m = -1e30f;
  for (int s = tid; s < Kk; s += 256) m = fmaxf(m, lg[s]);
  red[tid] = m; __syncthreads();
  for (int st = 128; st; st >>= 1) { if (tid < st) red[tid] = fmaxf(red[tid], red[tid+st]); __syncthreads(); }
  float M = red[0]; __syncthreads();
  float ss = 0.f;
  for (int s = tid; s < Kk; s += 256) ss += __expf(lg[s] - M);
  red[tid] = ss; __syncthreads();
  for (int st = 128; st; st >>= 1) { if (tid < st) red[tid] += red[tid+st]; __syncthreads(); }
  if (tid == 0) { fb[FO_BM + bg] = M; fb[FO_BINV + bg] = 1.f / red[0]; }
  const float* xm_b = fb + FO_XM + bg*64;
  float rK = 1.f / (float)Kk;
  if (tid < 32) {
    float a = spq_b[tid];
    for (int c = 0; c < 64; ++c)
      a += spq_w[tid*64 + c] * (xm_b[c] * rK);
    sqs[tid] = a;
  }
  __syncthreads();
  if (tid == 0) {
    float mx = -1e30f;
    for (int o = 0; o < 32; ++o) mx = fmaxf(mx, sqs[o]);
    float z = 0.f;
    for (int o = 0; o < 32; ++o) { float e = __expf(sqs[o] - mx); swq[o] = e; z += e; }
    float rz = 1.f / z;
    for (int o = 0; o < 32; ++o) swq[o] *= rz;
  }
  __syncthreads();
  if (tid < 64) {
    float a = 0.f;
    for (int o = 0; o < 32; ++o) a += swq[o] * spv_w[o*64 + tid];
    fb[FO_G + bg*64 + tid] = a;
  }
  if (tid == 64) {
    float gb = 0.f;
    for (int o = 0; o < 32; ++o) gb += swq[o] * spv_b[o];
    fb[FO_GB + bg] = gb;
  }
}

// ---------------- k_p2all: fused t + smap, barrier-free, all windows --------
template<int WIN, int CH, int CHUNK, int ITERS>
DEV void p2_body(int idx) {
  using W = WP<WIN>;
  constexpr int K = W::K, P = W::P, CK = 64*K, WI = W::WI, QOFF = W::QOFF,
                BOFF = W::BOFF;
  float* fb = g_fb;
  const bf16* ex = (const bf16*)g_ex_u;
  int bi = idx / CH, ch = idx - bi*CH;
  int n = bi / P, bl = bi - n*P; int bg = BOFF + bi;
  int base = ch*CHUNK;
  int send = (base + CHUNK < K) ? base + CHUNK : K;
  const bf16* exn = ex + (size_t)(n*192 + WI*64)*25600;
  const float* qin = fb + FO_Q + QOFF + (size_t)bi*K;
  float* so = fb + FO_SMAP + QOFF + (size_t)bi*K;
  float M = fb[FO_BM + bg], inv = fb[FO_BINV + bg];
  float gbs = fb[FO_GB + bg];
  int tid = threadIdx.x, lane = tid & 63;
  float gs[64];
#pragma unroll
  for (int j = 0; j < 64; ++j) gs[j] = fb[FO_G + bg*64 + j];
  float part[64];
#pragma unroll
  for (int j = 0; j < 64; ++j) part[j] = 0.f;
  for (int it = 0; it < ITERS; ++it) {
    int sp = base + it*256 + tid;
    if (sp < send) {
      float qv = __expf(qin[sp] - M) * inv;
      int f = bl*CK + sp;
      int c, kidx, p; decomp<WIN>(f, c, kidx, p);
      float dot = 0.f;
#pragma unroll
      for (int j = 0; j < 64; ++j) {
        float v = __bfloat162float(exn[c*25600 + pix<WIN>(kidx, p)]);
        part[j] += qv * v;
        dot += gs[j] * v;
        stepK<WIN>(c, kidx, p);
      }
      so[sp] = 1.f / (1.f + __expf(-(dot + gbs)));
    }
  }
  wave_reduce64_atomic(fb + FO_T + bg*64, part, lane);
}

__global__ __launch_bounds__(256, 2)
void k_p2all() {
  int blk = blockIdx.x;
  if (blk < 400)      p2_body<1,25,1024,4>(blk);
  else if (blk < 832) p2_body<3, 3, 972,4>(blk - 400);
  else                p2_body<5, 2, 512,2>(blk - 832);
}

// ---------------- k_zln: wz -> z -> LayerNorm -> sigA ----------------
__global__ __launch_bounds__(64)
void k_zln(const float* __restrict__ chv_w, const float* __restrict__ chv_b,
           const float* __restrict__ chz_w, const float* __restrict__ chz_b,
           const float* __restrict__ ln_g,  const float* __restrict__ ln_b) {
  float* fb = g_fb;
  __shared__ float wzs[32]; __shared__ float zsh[64]; __shared__ float mom[2];
  int bg = blockIdx.x, tid = threadIdx.x;
  const float* t_b = fb + FO_T + bg*64;
  if (tid < 32) {
    float a = chv_b[tid];
    for (int c = 0; c < 64; ++c)
      a += chv_w[tid*64 + c] * t_b[c];
    wzs[tid] = a;
  }
  __syncthreads();
  float zv = chz_b[tid];
  for (int o = 0; o < 32; ++o)
    zv += chz_w[tid*32 + o] * wzs[o];
  zsh[tid] = zv;
  __syncthreads();
  if (tid == 0) {
    float mu = 0.f;
    for (int j = 0; j < 64; ++j) mu += zsh[j];
    mu *= (1.f/64.f);
    float m2 = 0.f;
    for (int j = 0; j < 64; ++j) { float d = zsh[j] - mu; m2 += d*d; }
    m2 *= (1.f/64.f);
    mom[0] = mu; mom[1] = rsqrtf(m2 + 1e-5f);
  }
  __syncthreads();
  float zn = (zv - mom[0]) * mom[1] * ln_g[tid] + ln_b[tid];
  fb[FO_SIGA + bg*64 + tid] = 1.f / (1.f + __expf(-zn));
}

// ---------------- k_final: gates -> extT (bf16, swizzled LDS) -> MFMA conv ----
// siga/smap read directly from global (L1/L2-resident); no sigaS staging.
template<int WIN> DEV void gate_rows2(int n, int h, int w, int px,
                                      const bf16* __restrict__ ex,
                                      const float* __restrict__ fb,
                                      bf16* extT) {
  using W = WP<WIN>;
  constexpr int SH = W::SH, KH = W::KH, K = W::K, P = W::P, WI = W::WI,
                QOFF = W::QOFF, BOFF = W::BOFF;
  int s = h*160 + w;
  const bf16* exr = ex + (size_t)(n*192 + WI*64)*25600 + s;
  const float* smap = fb + FO_SMAP + QOFF + (size_t)(n*P)*K;
  const float* sg   = fb + FO_SIGA + (size_t)(BOFF + n*P)*64;
  int swz = (px & 7) << 3;
  unsigned short ob[8];
  if constexpr (WIN == 1) {
    float sm = smap[s];
    for (int c0 = 0; c0 < 64; c0 += 8) {
#pragma unroll
      for (int cc = 0; cc < 8; ++cc) {
        int c = c0 + cc;
        float exv = __bfloat162float(exr[(size_t)c*25600]);
        ob[cc] = bfbits(exv * (1.f + sg[c] + sm));
      }
      store8bf(&extT[px*256 + ((WI*64 + c0) ^ swz)], ob);
    }
  } else {
    int phmin = (h >= KH) ? (h - KH)/SH + 1 : 0;
    int phmax = (WIN-1 < h/SH) ? WIN-1 : h/SH;
    int pwmin = (w >= KH) ? (w - KH)/SH + 1 : 0;
    int pwmax = (WIN-1 < w/SH) ? WIN-1 : w/SH;
    int cf[4]; int s0s[4]; int np = 0;
    for (int ph = phmin; ph <= phmax; ++ph)
      for (int pw = pwmin; pw <= pwmax; ++pw) {
        int ki = h - ph*SH, kj = w - pw*SH;
        unsigned base0 = (unsigned)((ki*KH + kj)*P + ph*WIN + pw);
        unsigned q = base0 / (unsigned)K;
        cf[np] = (int)q; s0s[np] = (int)(base0 - q*(unsigned)K); ++np;
      }
    float rc = 1.f / (float)np;
    int hi[4]; float smv[4];
#pragma unroll
    for (int t = 0; t < 4; ++t)
      if (t < np) { hi[t] = cf[t] >> 6; smv[t] = smap[hi[t]*K + s0s[t]]; }
    for (int c0 = 0; c0 < 64; c0 += 8) {
#pragma unroll
      for (int cc = 0; cc < 8; ++cc) {
        float gsum = 0.f;
#pragma unroll
        for (int t = 0; t < 4; ++t) {
          if (t < np) {
            int v = cf[t];
            int h2 = v >> 6;
            if (h2 != hi[t]) { hi[t] = h2; smv[t] = smap[h2*K + s0s[t]]; }
            gsum += sg[v] + smv[t];
            cf[t] = v + P;
          }
        }
        int c = c0 + cc;
        float exv = __bfloat162float(exr[(size_t)c*25600]);
        ob[cc] = bfbits(exv * (1.f + gsum * rc));
      }
      store8bf(&extT[px*256 + ((WI*64 + c0) ^ swz)], ob);
    }
  }
}

__global__ __launch_bounds__(256)
void k_final(const float* __restrict__ x, float* __restrict__ out) {
  const float* fb = g_fb;
  const bf16* ex = (const bf16*)g_ex_u;
  __shared__ __align__(16) bf16 extT[64*256];   // [px][k] swizzled, 32 KB
  int blk = blockIdx.x; int n = blk / 400; int s0 = (blk % 400) * 64;
  int tid = threadIdx.x;
  int rg = tid >> 6; int px = tid & 63;
  int s = s0 + px; int h = s / 160; int w = s - h*160;
  if (rg == 3) {
    int swz = (px & 7) << 3;
    unsigned short ob[8];
    for (int c0 = 0; c0 < 64; c0 += 8) {
#pragma unroll
      for (int cc = 0; cc < 8; ++cc)
        ob[cc] = bfbits(x[(size_t)(n*64 + c0 + cc)*25600 + s]);
      store8bf(&extT[px*256 + ((192 + c0) ^ swz)], ob);
    }
  } else if (rg == 0) gate_rows2<1>(n, h, w, px, ex, fb, extT);
  else if (rg == 1)   gate_rows2<3>(n, h, w, px, ex, fb, extT);
  else                gate_rows2<5>(n, h, w, px, ex, fb, extT);
  __syncthreads();

  // ---- MFMA: out[o][px] = sum_k W[k][o] * extT[px][k], K=256 ----
  int wv = tid >> 6; int l = tid & 63;
  int lx = l & 15, g = l >> 4;
  const u32x4* wfA = (const u32x4*)(fb + FO_WFRAG);
  u32x4 af[8];
#pragma unroll
  for (int ks = 0; ks < 8; ++ks) af[ks] = wfA[(wv*8 + ks)*64 + l];
  f32x4 acc[4];
#pragma unroll
  for (int pt = 0; pt < 4; ++pt) acc[pt] = f32x4{0.f, 0.f, 0.f, 0.f};
#pragma unroll
  for (int ks = 0; ks < 8; ++ks) {
#pragma unroll
    for (int pt = 0; pt < 4; ++pt) {
      int pxx = pt*16 + lx;
      const u32x4* bp = (const u32x4*)&extT[pxx*256 + ((ks*32 + g*8) ^ ((pxx & 7) << 3))];
      acc[pt] = __builtin_amdgcn_mfma_f32_16x16x32_bf16(
                  as_bf16x8(af[ks]), as_bf16x8(*bp), acc[pt], 0, 0, 0);
    }
  }
  float bia[4];
#pragma unroll
  for (int r = 0; r < 4; ++r) bia[r] = fb[FO_BCOMB + wv*16 + g*4 + r];
#pragma unroll
  for (int pt = 0; pt < 4; ++pt) {
#pragma unroll
    for (int r = 0; r < 4; ++r)
      out[(size_t)(n*64 + wv*16 + g*4 + r)*25600 + s0 + pt*16 + lx] = acc[pt][r] + bia[r];
  }
}

// ---------------- launch ----------------
extern "C" void kernel_launch(void* const* d_in, const int* in_sizes, int n_in,
                              void* d_out, int out_size, void* d_ws, size_t ws_size,
                              hipStream_t stream) {
  const float* x     = (const float*)d_in[0];
  const float* exp_w = (const float*)d_in[1];
  const float* exp_b = (const float*)d_in[2];
  const float* res_w = (const float*)d_in[3];
  const float* res_b = (const float*)d_in[4];
  const float* fus_w = (const float*)d_in[5];
  const float* fus_b = (const float*)d_in[6];
  const float* chv_w = (const float*)d_in[7];
  const float* chv_b = (const float*)d_in[8];
  const float* chq_w = (const float*)d_in[9];
  const float* chq_b = (const float*)d_in[10];
  const float* chz_w = (const float*)d_in[11];
  const float* chz_b = (const float*)d_in[12];
  const float* ln_g  = (const float*)d_in[13];
  const float* ln_b  = (const float*)d_in[14];
  const float* spv_w = (const float*)d_in[15];
  const float* spv_b = (const float*)d_in[16];
  const float* spq_w = (const float*)d_in[17];
  const float* spq_b = (const float*)d_in[18];
  float* out = (float*)d_out;

  k_prep<<<393, 256, 0, stream>>>(exp_w, exp_b, res_w, res_b, fus_w, fus_b);
  k_prep2<<<64, 256, 0, stream>>>();
  k_ex<<<6400, 256, 0, stream>>>(x);

  k_p1all<<<1632, 256, 0, stream>>>(chq_w, chq_b);

  k_bstats<<<560, 256, 0, stream>>>(spq_w, spq_b, spv_w, spv_b);

  k_p2all<<<1632, 256, 0, stream>>>();

  k_zln<<<560, 64, 0, stream>>>(chv_w, chv_b, chz_w, chz_b, ln_g, ln_b);

  k_final<<<6400, 256, 0, stream>>>(x, out);
}